// Round 3
// baseline (1843.358 us; speedup 1.0000x reference)
//
#include <hip/hip_runtime.h>

#define LOG2E 1.4426950408889634f

// broadcast lane `srclane`'s value to all lanes via v_readlane (SGPR result).
// srclane may be a wave-uniform dynamic value (SGPR lane select).
__device__ __forceinline__ float rl(float v, int srclane) {
  return __int_as_float(__builtin_amdgcn_readlane(__float_as_int(v), srclane));
}

// quad broadcast via DPP quad_perm (VALU-latency cross-lane within groups of 4)
template<int CTL>
__device__ __forceinline__ float qb(float v) {
  return __int_as_float(__builtin_amdgcn_update_dpp(0, __float_as_int(v), CTL, 0xF, 0xF, true));
}

__device__ __forceinline__ float fast_rcp(float x)  { return __builtin_amdgcn_rcpf(x); }
__device__ __forceinline__ float fast_exp2(float x) { return __builtin_amdgcn_exp2f(x); }

__device__ __forceinline__ float sigf(float x) {
  return fast_rcp(1.0f + fast_exp2(-LOG2E * x));
}
__device__ __forceinline__ float tanhfast(float x) {
  return fmaf(fast_rcp(1.0f + fast_exp2(-2.0f * LOG2E * x)), 2.0f, -1.0f);
}

// One bidirectional-LSTM layer. grid = 256 blocks (b*2+dir), block = 192 (3 waves).
// Wave 0: consumer — runs the recurrence.
// Waves 1,2: producers — bulk-load a 64-step x chunk into registers (one row per
//   lane), compute pre-scaled, pre-negated xW(t)+b, and write the LDS ring.
// Ring layout: [lane][step] with XOR swizzle (s ^ (4*lane & 63)) so the consumer
//   reads 4 steps per ds_read_b128 (prefetched one group ahead — hides the
//   ~120-cyc LDS latency that R2 exposed per step) and producers ds_write_b128.
// Lane layout: j = lane>>2 (hidden 0..15), g = lane&3 (gate i,f,g,o); row r = g*16+j.
template<int IN, bool LAST>
__global__ __launch_bounds__(192) void bilstm_layer(
    const float* __restrict__ x,     // (B,T,IN)
    const float* __restrict__ Wih,   // (2,64,IN)
    const float* __restrict__ Whh,   // (2,64,16)
    const float* __restrict__ bias,  // (2,64)
    float* __restrict__ out)         // (B,T,32) or (B,256,32) if LAST
{
  constexpr int T = 2048;
  constexpr int C = 64;          // ring chunk (steps)
  constexpr int NCH = T / C;
  constexpr int NV4 = IN / 4;    // float4 loads per row
  const int b    = blockIdx.x >> 1;
  const int dir  = blockIdx.x & 1;
  const int tid  = threadIdx.x;
  const int wave = tid >> 6;
  const int lane = tid & 63;
  const int g = lane & 3;
  const int j = lane >> 2;
  const int r = g * 16 + j;
  const int sw = (lane << 2) & 63;   // xor swizzle (dwords), multiple of 4
  // fold activation arg scale into weights/bias: gate lanes get log2e, g-gate
  // gets 2*log2e (tanh = 2*sigmoid(2x)-1), all negated so e = exp2(acc) directly.
  const float ksc = (g == 2) ? 2.0f * LOG2E : LOG2E;

  __shared__ float ring[2][C * 64];

  if (wave >= 1) {
    // ---------------- producers ----------------
    const int pw = wave - 1;     // 0: steps 0..31, 1: steps 32..63
    float wih[IN];
    const float* wr = Wih + (size_t)(dir * 64 + r) * IN;
#pragma unroll
    for (int k = 0; k < IN; ++k) wih[k] = -ksc * wr[k];
    const float bneg = -ksc * bias[dir * 64 + r];
    const float* xb = x + (size_t)b * T * IN;
    for (int chunk = 0; chunk <= NCH; ++chunk) {
      if (chunk < NCH) {
        const int tt0  = chunk * C;
        const int tmin = dir ? (T - C - tt0) : tt0;   // chunk covers rows [tmin, tmin+C)
        const float* src = xb + (size_t)(tmin + lane) * IN;
        float4 xr[NV4];
#pragma unroll
        for (int v = 0; v < NV4; ++v) xr[v] = *(const float4*)(src + 4 * v);
        float* bufl = &ring[chunk & 1][lane * 64];
        for (int s0 = pw * 32; s0 < pw * 32 + 32; s0 += 4) {
          float4 acc4;
          float* ap = &acc4.x;
#pragma unroll
          for (int u = 0; u < 4; ++u) {
            const int s   = s0 + u;
            const int row = dir ? (C - 1 - s) : s;    // lane holding x for this step
            float a0 = bneg, a1 = 0.0f;
#pragma unroll
            for (int v = 0; v < NV4; ++v) {
              a0 = fmaf(rl(xr[v].x, row), wih[4 * v + 0], a0);
              a1 = fmaf(rl(xr[v].y, row), wih[4 * v + 1], a1);
              a0 = fmaf(rl(xr[v].z, row), wih[4 * v + 2], a0);
              a1 = fmaf(rl(xr[v].w, row), wih[4 * v + 3], a1);
            }
            ap[u] = a0 + a1;   // = -ksc*(Wih·x_t + b)
          }
          *(float4*)(bufl + (s0 ^ sw)) = acc4;        // ds_write_b128, swizzled
        }
      }
      __syncthreads();
    }
  } else {
    // ---------------- consumer (recurrence) ----------------
    float whh[16];
    const float* wr = Whh + (size_t)(dir * 64 + r) * 16;
#pragma unroll
    for (int k = 0; k < 16; ++k) whh[k] = -ksc * wr[k];
    // keep c scaled: ct = -2*log2e * c. Fold the extra -2*log2e into the g-gate
    // activation constants so the c-update needs no extra multiply before exp2.
    const float amul = (g == 2) ? -4.0f * LOG2E : 1.0f;
    const float aadd = (g == 2) ?  2.0f * LOG2E : 0.0f;
    float ct = 0.0f, h = 0.0f;
    float* opN = out + ((size_t)b * T)   * 32 + dir * 16 + j;
    float* opL = out + ((size_t)b * 256) * 32 + dir * 16 + j;
    __syncthreads();   // wait for producers' first chunk
    for (int chunk = 0; chunk < NCH; ++chunk) {
      const float* bufl = &ring[chunk & 1][lane * 64];
      float4 cur = *(const float4*)(bufl + sw);       // group 0 (swizzled)
      for (int m = 0; m < 16; ++m) {
        const float4 nxt = *(const float4*)(bufl + ((((m + 1) & 15) * 4) ^ sw));
        const float* cp = &cur.x;
#pragma unroll
        for (int u = 0; u < 4; ++u) {
          const int tt = chunk * C + m * 4 + u;
          const int t  = dir ? (T - 1 - tt) : tt;
          // 64x16 matvec: 4 independent FMA chains, h broadcast via readlane.
          // a0 seeded with the prefetched -ksc*(xW+b) term.
          float a0 = cp[u], a1 = 0.f, a2 = 0.f, a3 = 0.f;
#pragma unroll
          for (int k = 0; k < 4; ++k) {
            a0 = fmaf(rl(h, 16 * k),      whh[4 * k],     a0);
            a1 = fmaf(rl(h, 16 * k + 4),  whh[4 * k + 1], a1);
            a2 = fmaf(rl(h, 16 * k + 8),  whh[4 * k + 2], a2);
            a3 = fmaf(rl(h, 16 * k + 12), whh[4 * k + 3], a3);
          }
          const float acc = (a0 + a1) + (a2 + a3);           // = -ksc * preact
          const float e   = fast_exp2(acc);
          const float sgm = fast_rcp(1.0f + e);              // sigmoid(ksc'*P)
          const float act = fmaf(sgm, amul, aadd);           // sigmoid / -2log2e*tanh
          const float ia = qb<0x00>(act);
          const float fa = qb<0x55>(act);
          const float ga = qb<0xAA>(act);                    // = -2log2e * g
          const float oa = qb<0xFF>(act);
          ct = fmaf(fa, ct, ia * ga);                        // ct = -2log2e * c
          const float e2 = fast_exp2(ct);
          const float tc = fmaf(fast_rcp(1.0f + e2), 2.0f, -1.0f);  // tanh(c)
          h = oa * tc;
          if (g == 0) {
            if (!LAST) {
              opN[(size_t)t * 32] = h;
            } else if ((t & 7) == 7) {
              opL[(size_t)(t >> 3) * 32] = h;
            }
          }
        }
        cur = nxt;
      }
      __syncthreads();
    }
  }
}

// Precompute layer-0 xW for the unidirectional stack: xw0[b][t][g] = ub0[g] + uWih0[g]·x
__global__ __launch_bounds__(256) void uni_xw0(
    const float* __restrict__ dsb,    // (B,256,32)
    const float* __restrict__ uWih0,  // (4,32)
    const float* __restrict__ ub,     // (4,4) — row 0 used
    float* __restrict__ xw0)          // (B,256,4)
{
  const int b = blockIdx.x;
  const int t = threadIdx.x;
  const float* xp = dsb + ((size_t)b * 256 + t) * 32;
  float xv[32];
#pragma unroll
  for (int k = 0; k < 32; k += 4) {
    const float4 v = *(const float4*)(xp + k);
    xv[k] = v.x; xv[k + 1] = v.y; xv[k + 2] = v.z; xv[k + 3] = v.w;
  }
  float4 o;
  float* po = &o.x;
#pragma unroll
  for (int gg = 0; gg < 4; ++gg) {
    float a0 = ub[gg], a1 = 0.f;
#pragma unroll
    for (int k = 0; k < 32; k += 2) {
      a0 = fmaf(uWih0[gg * 32 + k],     xv[k],     a0);
      a1 = fmaf(uWih0[gg * 32 + k + 1], xv[k + 1], a1);
    }
    po[gg] = a0 + a1;
  }
  *(float4*)(xw0 + ((size_t)b * 256 + t) * 4) = o;
}

// Fused 4-layer unidirectional stack (HU=1), step-synchronous across layers.
// lane = batch element. grid 2 x 64.
__global__ __launch_bounds__(64) void uni_stack(
    const float* __restrict__ xw0,   // (B,256,4) pre-biased layer-0 xW
    const float* __restrict__ uWih,  // (3,4,1)
    const float* __restrict__ uWhh,  // (4,4,1)
    const float* __restrict__ ub,    // (4,4)
    float* __restrict__ out)         // (B,256)
{
  const int b = blockIdx.x * 64 + threadIdx.x;
  float whh[4][4], wih[3][4], bs[3][4];
#pragma unroll
  for (int l = 0; l < 4; ++l)
#pragma unroll
    for (int gg = 0; gg < 4; ++gg) whh[l][gg] = uWhh[l * 4 + gg];
#pragma unroll
  for (int l = 0; l < 3; ++l)
#pragma unroll
    for (int gg = 0; gg < 4; ++gg) {
      wih[l][gg] = uWih[l * 4 + gg];
      bs[l][gg]  = ub[(l + 1) * 4 + gg];
    }
  float h[4] = {0, 0, 0, 0}, c[4] = {0, 0, 0, 0};
  const float4* xp = (const float4*)(xw0 + (size_t)b * 256 * 4);
  float* op = out + (size_t)b * 256;
  for (int t = 0; t < 256; ++t) {
    const float4 xw = xp[t];
    {
      const float i0 = sigf(fmaf(whh[0][0], h[0], xw.x));
      const float f0 = sigf(fmaf(whh[0][1], h[0], xw.y));
      const float g0 = tanhfast(fmaf(whh[0][2], h[0], xw.z));
      const float o0 = sigf(fmaf(whh[0][3], h[0], xw.w));
      c[0] = fmaf(f0, c[0], i0 * g0);
      h[0] = o0 * tanhfast(c[0]);
    }
#pragma unroll
    for (int l = 1; l < 4; ++l) {
      const float xin = h[l - 1];
      const float pi  = fmaf(whh[l][0], h[l], fmaf(wih[l - 1][0], xin, bs[l - 1][0]));
      const float pf  = fmaf(whh[l][1], h[l], fmaf(wih[l - 1][1], xin, bs[l - 1][1]));
      const float pg  = fmaf(whh[l][2], h[l], fmaf(wih[l - 1][2], xin, bs[l - 1][2]));
      const float po_ = fmaf(whh[l][3], h[l], fmaf(wih[l - 1][3], xin, bs[l - 1][3]));
      const float il = sigf(pi), fl = sigf(pf), gl = tanhfast(pg), ol = sigf(po_);
      c[l] = fmaf(fl, c[l], il * gl);
      h[l] = ol * tanhfast(c[l]);
    }
    op[t] = h[3];
  }
}

extern "C" void kernel_launch(void* const* d_in, const int* in_sizes, int n_in,
                              void* d_out, int out_size, void* d_ws, size_t ws_size,
                              hipStream_t stream)
{
  (void)in_sizes; (void)n_in; (void)out_size; (void)ws_size;
  const float* r_c_s = (const float*)d_in[0];
  const float* bWih0 = (const float*)d_in[1];
  const float* bWih  = (const float*)d_in[2];
  const float* bWhh  = (const float*)d_in[3];
  const float* bb    = (const float*)d_in[4];
  const float* uWih0 = (const float*)d_in[5];
  const float* uWih  = (const float*)d_in[6];
  const float* uWhh  = (const float*)d_in[7];
  const float* ub    = (const float*)d_in[8];
  float* outp = (float*)d_out;

  // workspace layout (floats): two (B,T,32) ping-pong, (B,256,32) downsample, (B,256,4) uni-xW
  float* x0  = (float*)d_ws;
  float* x1  = x0  + (size_t)128 * 2048 * 32;
  float* dsb = x1  + (size_t)128 * 2048 * 32;
  float* xw0 = dsb + (size_t)128 * 256 * 32;

  const dim3 grid(256), block(192);
  bilstm_layer<24, false><<<grid, block, 0, stream>>>(r_c_s, bWih0,               bWhh + 0,               bb + 0,          x0);
  bilstm_layer<32, false><<<grid, block, 0, stream>>>(x0,    bWih + 0 * 2*64*32,  bWhh + 1 * 2*64*16,     bb + 1 * 2*64,   x1);
  bilstm_layer<32, false><<<grid, block, 0, stream>>>(x1,    bWih + 1 * 2*64*32,  bWhh + 2 * 2*64*16,     bb + 2 * 2*64,   x0);
  bilstm_layer<32, true ><<<grid, block, 0, stream>>>(x0,    bWih + 2 * 2*64*32,  bWhh + 3 * 2*64*16,     bb + 3 * 2*64,   dsb);
  uni_xw0 <<<dim3(128), dim3(256), 0, stream>>>(dsb, uWih0, ub, xw0);
  uni_stack<<<dim3(2),   dim3(64),  0, stream>>>(xw0, uWih, uWhh, ub, outp);
}

// Round 4
// 1315.722 us; speedup vs baseline: 1.4010x; 1.4010x over previous
//
#include <hip/hip_runtime.h>

#define LOG2E 1.4426950408889634f

// broadcast lane `srclane`'s value to all lanes via v_readlane (SGPR result).
__device__ __forceinline__ float rl(float v, int srclane) {
  return __int_as_float(__builtin_amdgcn_readlane(__float_as_int(v), srclane));
}
__device__ __forceinline__ unsigned rlu(unsigned v, int srclane) {
  return (unsigned)__builtin_amdgcn_readlane((int)v, srclane);
}

// quad broadcast via DPP quad_perm
template<int CTL>
__device__ __forceinline__ float qb(float v) {
  return __int_as_float(__builtin_amdgcn_update_dpp(0, __float_as_int(v), CTL, 0xF, 0xF, true));
}

__device__ __forceinline__ float fast_rcp(float x)  { return __builtin_amdgcn_rcpf(x); }
__device__ __forceinline__ float fast_exp2(float x) { return __builtin_amdgcn_exp2f(x); }

__device__ __forceinline__ float sigf(float x) {
  return fast_rcp(1.0f + fast_exp2(-LOG2E * x));
}
__device__ __forceinline__ float tanhfast(float x) {
  return fmaf(fast_rcp(1.0f + fast_exp2(-2.0f * LOG2E * x)), 2.0f, -1.0f);
}

#if defined(__has_builtin)
#if __has_builtin(__builtin_amdgcn_fdot2)
#define USE_FDOT2 1
#endif
#endif

typedef _Float16 half2_t __attribute__((ext_vector_type(2)));

// One bidirectional-LSTM layer. grid = 256 blocks (b*2+dir), block = 192 (3 waves).
// Wave 0: consumer — pure recurrence: ds_read pre, f16-dot2 matvec (8 readlane +
//   8 v_dot2_f32_f16 instead of 16 rl + 16 fma), gates, ds_write h. No global
//   access, no branches beyond the loop.
// Waves 1,2: producers — (a) bulk-load a 64-step x chunk into registers and
//   compute pre-scaled, pre-negated xW(t)+b into the xW ring (R2 pattern);
//   (b) drain the h ring (written by consumer, 1 chunk behind) to global.
// Lane layout: j = lane>>2 (hidden 0..15), g = lane&3 (gate i,f,g,o); row r = g*16+j.
template<int IN, bool LAST>
__global__ __launch_bounds__(192) void bilstm_layer(
    const float* __restrict__ x,     // (B,T,IN)
    const float* __restrict__ Wih,   // (2,64,IN)
    const float* __restrict__ Whh,   // (2,64,16)
    const float* __restrict__ bias,  // (2,64)
    float* __restrict__ out)         // (B,T,32) or (B,256,32) if LAST
{
  constexpr int T = 2048;
  constexpr int C = 64;          // ring chunk (steps)
  constexpr int NCH = T / C;
  constexpr int NSLOT = NCH + 2; // pipeline slots (xW prod -> consume -> h drain)
  constexpr int NV4 = IN / 4;    // float4 loads per row
  const int b    = blockIdx.x >> 1;
  const int dir  = blockIdx.x & 1;
  const int tid  = threadIdx.x;
  const int wave = tid >> 6;
  const int lane = tid & 63;
  const int g = lane & 3;
  const int j = lane >> 2;
  const int r = g * 16 + j;
  // fold activation arg scale into weights/bias: gate lanes get log2e, g-gate
  // gets 2*log2e (tanh = 2*sigmoid(2x)-1), all negated so e = exp2(acc) directly.
  const float ksc = (g == 2) ? 2.0f * LOG2E : LOG2E;

  __shared__ float ring [2][C * 64];   // xW staging (producers -> consumer)
  __shared__ float ring2[2][C * 65];   // h staging (consumer -> producers), pad 65 for banks

  if (wave >= 1) {
    // ---------------- producers ----------------
    const int pw = wave - 1;     // 0 or 1
    float wih[IN];
    const float* wr = Wih + (size_t)(dir * 64 + r) * IN;
#pragma unroll
    for (int k = 0; k < IN; ++k) wih[k] = -ksc * wr[k];
    const float bneg = -ksc * bias[dir * 64 + r];
    const float* xb = x + (size_t)b * T * IN;
    const int sl = lane >> 4;    // h-drain: step sub-row 0..3
    const int jj = lane & 15;    // h-drain: hidden index
    for (int c = 0; c < NSLOT; ++c) {
      // phase A: produce xW(chunk c) — R2 pattern (proven)
      if (c < NCH) {
        const int tt0  = c * C;
        const int tmin = dir ? (T - C - tt0) : tt0;   // chunk covers rows [tmin, tmin+C)
        const float* src = xb + (size_t)(tmin + lane) * IN;
        float4 xr[NV4];
#pragma unroll
        for (int v = 0; v < NV4; ++v) xr[v] = *(const float4*)(src + 4 * v);
        float* buf = ring[c & 1];
        for (int s = pw; s < C; s += 2) {
          const int row = dir ? (C - 1 - s) : s;      // lane holding x for this step
          float a0 = bneg, a1 = 0.0f;
#pragma unroll
          for (int v = 0; v < NV4; ++v) {
            a0 = fmaf(rl(xr[v].x, row), wih[4 * v + 0], a0);
            a1 = fmaf(rl(xr[v].y, row), wih[4 * v + 1], a1);
            a0 = fmaf(rl(xr[v].z, row), wih[4 * v + 2], a0);
            a1 = fmaf(rl(xr[v].w, row), wih[4 * v + 3], a1);
          }
          buf[s * 64 + lane] = a0 + a1;   // = -ksc*(Wih·x_t + b)
        }
      }
      // phase B: drain h(chunk c-2) to global
      if (c >= 2 && c - 2 < NCH) {
        const int d = c - 2;
        const float* r2 = ring2[d & 1];
        for (int s0 = pw * 32; s0 < pw * 32 + 32; s0 += 4) {
          const int s  = s0 + sl;
          const float hv = r2[s * 65 + 4 * jj];
          const int tt = d * C + s;
          const int t  = dir ? (T - 1 - tt) : tt;
          if (!LAST) {
            out[((size_t)b * T + t) * 32 + dir * 16 + jj] = hv;
          } else if ((t & 7) == 7) {
            out[((size_t)b * 256 + (t >> 3)) * 32 + dir * 16 + jj] = hv;
          }
        }
      }
      __syncthreads();
    }
  } else {
    // ---------------- consumer (recurrence) ----------------
#if defined(USE_FDOT2)
    half2_t w2[8];
    {
      const float* wr = Whh + (size_t)(dir * 64 + r) * 16;
#pragma unroll
      for (int p = 0; p < 8; ++p) {
        half2_t w;
        w.x = (_Float16)(-ksc * wr[2 * p]);
        w.y = (_Float16)(-ksc * wr[2 * p + 1]);
        w2[p] = w;
      }
    }
#else
    float whh[16];
    const float* wr = Whh + (size_t)(dir * 64 + r) * 16;
#pragma unroll
    for (int k = 0; k < 16; ++k) whh[k] = -ksc * wr[k];
#endif
    // keep c scaled: ct = -2*log2e * c; fold the extra scale into g-gate consts.
    const float amul = (g == 2) ? -4.0f * LOG2E : 1.0f;
    const float aadd = (g == 2) ?  2.0f * LOG2E : 0.0f;
    float ct = 0.0f, h = 0.0f;
    unsigned hpk = 0;   // f16 pair (h_{2p}, h_{2p+1}) in lanes 8p (for readlane)
    for (int c = 0; c < NSLOT; ++c) {
      if (c >= 1 && c <= NCH) {
        const float* buf  = ring [(c - 1) & 1];
        float*       hbuf = ring2[(c - 1) & 1];
        float pre = buf[lane];
#pragma unroll 4
        for (int s = 0; s < C; ++s) {
          const float pre_n = buf[(((s + 1) & (C - 1)) * 64) + lane];  // next-step prefetch
#if defined(USE_FDOT2)
          // 64x16 matvec as 4 chains of 2 f16 dot2 (f32 accumulate); h pairs
          // broadcast from lanes 8p via readlane.
          float a0 = __builtin_amdgcn_fdot2(__builtin_bit_cast(half2_t, rlu(hpk,  0)), w2[0], pre, false);
          float a1 = __builtin_amdgcn_fdot2(__builtin_bit_cast(half2_t, rlu(hpk,  8)), w2[1], 0.f, false);
          float a2 = __builtin_amdgcn_fdot2(__builtin_bit_cast(half2_t, rlu(hpk, 16)), w2[2], 0.f, false);
          float a3 = __builtin_amdgcn_fdot2(__builtin_bit_cast(half2_t, rlu(hpk, 24)), w2[3], 0.f, false);
          a0 = __builtin_amdgcn_fdot2(__builtin_bit_cast(half2_t, rlu(hpk, 32)), w2[4], a0, false);
          a1 = __builtin_amdgcn_fdot2(__builtin_bit_cast(half2_t, rlu(hpk, 40)), w2[5], a1, false);
          a2 = __builtin_amdgcn_fdot2(__builtin_bit_cast(half2_t, rlu(hpk, 48)), w2[6], a2, false);
          a3 = __builtin_amdgcn_fdot2(__builtin_bit_cast(half2_t, rlu(hpk, 56)), w2[7], a3, false);
#else
          float a0 = pre, a1 = 0.f, a2 = 0.f, a3 = 0.f;
#pragma unroll
          for (int k = 0; k < 4; ++k) {
            a0 = fmaf(rl(h, 16 * k),      whh[4 * k],     a0);
            a1 = fmaf(rl(h, 16 * k + 4),  whh[4 * k + 1], a1);
            a2 = fmaf(rl(h, 16 * k + 8),  whh[4 * k + 2], a2);
            a3 = fmaf(rl(h, 16 * k + 12), whh[4 * k + 3], a3);
          }
#endif
          const float acc = (a0 + a1) + (a2 + a3);           // = -ksc * preact
          const float e   = fast_exp2(acc);
          const float sgm = fast_rcp(1.0f + e);              // sigmoid(ksc'*P)
          const float act = fmaf(sgm, amul, aadd);           // sigmoid / -2log2e*tanh
          const float ia = qb<0x00>(act);
          const float fa = qb<0x55>(act);
          const float ga = qb<0xAA>(act);                    // = -2log2e * g
          const float oa = qb<0xFF>(act);
          ct = fmaf(fa, ct, ia * ga);                        // ct = -2log2e * c
          const float e2 = fast_exp2(ct);
          const float tc = fmaf(fast_rcp(1.0f + e2), 2.0f, -1.0f);  // tanh(c)
          h = oa * tc;
#if defined(USE_FDOT2)
          // pack (h_j, h_{j+1}) f16 pair: cvt, DPP row_shr:4 (pull quad j+1), combine
          const unsigned lo = (unsigned)__builtin_bit_cast(unsigned short, (_Float16)h);
          const unsigned hi = (unsigned)__builtin_amdgcn_update_dpp(0, (int)lo, 0x114, 0xF, 0xF, true);
          hpk = lo | (hi << 16);
#endif
          hbuf[s * 65 + lane] = h;                           // all lanes (h quad-replicated)
          pre = pre_n;
        }
      }
      __syncthreads();
    }
  }
}

// Precompute layer-0 xW for the unidirectional stack: xw0[b][t][g] = ub0[g] + uWih0[g]·x
__global__ __launch_bounds__(256) void uni_xw0(
    const float* __restrict__ dsb,    // (B,256,32)
    const float* __restrict__ uWih0,  // (4,32)
    const float* __restrict__ ub,     // (4,4) — row 0 used
    float* __restrict__ xw0)          // (B,256,4)
{
  const int b = blockIdx.x;
  const int t = threadIdx.x;
  const float* xp = dsb + ((size_t)b * 256 + t) * 32;
  float xv[32];
#pragma unroll
  for (int k = 0; k < 32; k += 4) {
    const float4 v = *(const float4*)(xp + k);
    xv[k] = v.x; xv[k + 1] = v.y; xv[k + 2] = v.z; xv[k + 3] = v.w;
  }
  float4 o;
  float* po = &o.x;
#pragma unroll
  for (int gg = 0; gg < 4; ++gg) {
    float a0 = ub[gg], a1 = 0.f;
#pragma unroll
    for (int k = 0; k < 32; k += 2) {
      a0 = fmaf(uWih0[gg * 32 + k],     xv[k],     a0);
      a1 = fmaf(uWih0[gg * 32 + k + 1], xv[k + 1], a1);
    }
    po[gg] = a0 + a1;
  }
  *(float4*)(xw0 + ((size_t)b * 256 + t) * 4) = o;
}

// Fused 4-layer unidirectional stack (HU=1), step-synchronous across layers.
__global__ __launch_bounds__(64) void uni_stack(
    const float* __restrict__ xw0,   // (B,256,4) pre-biased layer-0 xW
    const float* __restrict__ uWih,  // (3,4,1)
    const float* __restrict__ uWhh,  // (4,4,1)
    const float* __restrict__ ub,    // (4,4)
    float* __restrict__ out)         // (B,256)
{
  const int b = blockIdx.x * 64 + threadIdx.x;
  float whh[4][4], wih[3][4], bs[3][4];
#pragma unroll
  for (int l = 0; l < 4; ++l)
#pragma unroll
    for (int gg = 0; gg < 4; ++gg) whh[l][gg] = uWhh[l * 4 + gg];
#pragma unroll
  for (int l = 0; l < 3; ++l)
#pragma unroll
    for (int gg = 0; gg < 4; ++gg) {
      wih[l][gg] = uWih[l * 4 + gg];
      bs[l][gg]  = ub[(l + 1) * 4 + gg];
    }
  float h[4] = {0, 0, 0, 0}, c[4] = {0, 0, 0, 0};
  const float4* xp = (const float4*)(xw0 + (size_t)b * 256 * 4);
  float* op = out + (size_t)b * 256;
  for (int t = 0; t < 256; ++t) {
    const float4 xw = xp[t];
    {
      const float i0 = sigf(fmaf(whh[0][0], h[0], xw.x));
      const float f0 = sigf(fmaf(whh[0][1], h[0], xw.y));
      const float g0 = tanhfast(fmaf(whh[0][2], h[0], xw.z));
      const float o0 = sigf(fmaf(whh[0][3], h[0], xw.w));
      c[0] = fmaf(f0, c[0], i0 * g0);
      h[0] = o0 * tanhfast(c[0]);
    }
#pragma unroll
    for (int l = 1; l < 4; ++l) {
      const float xin = h[l - 1];
      const float pi  = fmaf(whh[l][0], h[l], fmaf(wih[l - 1][0], xin, bs[l - 1][0]));
      const float pf  = fmaf(whh[l][1], h[l], fmaf(wih[l - 1][1], xin, bs[l - 1][1]));
      const float pg  = fmaf(whh[l][2], h[l], fmaf(wih[l - 1][2], xin, bs[l - 1][2]));
      const float po_ = fmaf(whh[l][3], h[l], fmaf(wih[l - 1][3], xin, bs[l - 1][3]));
      const float il = sigf(pi), fl = sigf(pf), gl = tanhfast(pg), ol = sigf(po_);
      c[l] = fmaf(fl, c[l], il * gl);
      h[l] = ol * tanhfast(c[l]);
    }
    op[t] = h[3];
  }
}

extern "C" void kernel_launch(void* const* d_in, const int* in_sizes, int n_in,
                              void* d_out, int out_size, void* d_ws, size_t ws_size,
                              hipStream_t stream)
{
  (void)in_sizes; (void)n_in; (void)out_size; (void)ws_size;
  const float* r_c_s = (const float*)d_in[0];
  const float* bWih0 = (const float*)d_in[1];
  const float* bWih  = (const float*)d_in[2];
  const float* bWhh  = (const float*)d_in[3];
  const float* bb    = (const float*)d_in[4];
  const float* uWih0 = (const float*)d_in[5];
  const float* uWih  = (const float*)d_in[6];
  const float* uWhh  = (const float*)d_in[7];
  const float* ub    = (const float*)d_in[8];
  float* outp = (float*)d_out;

  // workspace layout (floats): two (B,T,32) ping-pong, (B,256,32) downsample, (B,256,4) uni-xW
  float* x0  = (float*)d_ws;
  float* x1  = x0  + (size_t)128 * 2048 * 32;
  float* dsb = x1  + (size_t)128 * 2048 * 32;
  float* xw0 = dsb + (size_t)128 * 256 * 32;

  const dim3 grid(256), block(192);
  bilstm_layer<24, false><<<grid, block, 0, stream>>>(r_c_s, bWih0,               bWhh + 0,               bb + 0,          x0);
  bilstm_layer<32, false><<<grid, block, 0, stream>>>(x0,    bWih + 0 * 2*64*32,  bWhh + 1 * 2*64*16,     bb + 1 * 2*64,   x1);
  bilstm_layer<32, false><<<grid, block, 0, stream>>>(x1,    bWih + 1 * 2*64*32,  bWhh + 2 * 2*64*16,     bb + 2 * 2*64,   x0);
  bilstm_layer<32, true ><<<grid, block, 0, stream>>>(x0,    bWih + 2 * 2*64*32,  bWhh + 3 * 2*64*16,     bb + 3 * 2*64,   dsb);
  uni_xw0 <<<dim3(128), dim3(256), 0, stream>>>(dsb, uWih0, ub, xw0);
  uni_stack<<<dim3(2),   dim3(64),  0, stream>>>(xw0, uWih, uWhh, ub, outp);
}

// Round 5
// 1118.684 us; speedup vs baseline: 1.6478x; 1.1761x over previous
//
#include <hip/hip_runtime.h>

#define LOG2E 1.4426950408889634f

typedef _Float16 h2t __attribute__((ext_vector_type(2)));

// broadcast lane `srclane`'s value to all lanes via v_readlane (SGPR result).
__device__ __forceinline__ float rl(float v, int srclane) {
  return __int_as_float(__builtin_amdgcn_readlane(__float_as_int(v), srclane));
}
__device__ __forceinline__ unsigned rlu(unsigned v, int srclane) {
  return (unsigned)__builtin_amdgcn_readlane((int)v, srclane);
}
// wave-uniform value -> SGPR (forces scalar-register storage)
__device__ __forceinline__ float rfl(float v) {
  return __int_as_float(__builtin_amdgcn_readfirstlane(__float_as_int(v)));
}

// quad broadcast via DPP quad_perm
template<int CTL>
__device__ __forceinline__ float qb(float v) {
  return __int_as_float(__builtin_amdgcn_update_dpp(0, __float_as_int(v), CTL, 0xF, 0xF, true));
}

__device__ __forceinline__ float fast_rcp(float x)  { return __builtin_amdgcn_rcpf(x); }
__device__ __forceinline__ float fast_exp2(float x) { return __builtin_amdgcn_exp2f(x); }

__device__ __forceinline__ float sigf(float x) {
  return fast_rcp(1.0f + fast_exp2(-LOG2E * x));
}
__device__ __forceinline__ float tanhfast(float x) {
  return fmaf(fast_rcp(1.0f + fast_exp2(-2.0f * LOG2E * x)), 2.0f, -1.0f);
}

// One bidirectional-LSTM layer. grid = 256 blocks (b*2+dir), block = 192 (3 waves).
// Wave 0: consumer — recurrence only. Single-wave issue cadence is ~4 cyc/instr,
//   so the step cost is ~4*(instruction count): matvec done as 8 readlane +
//   8 v_pk_fma_f16 (f16 pairs, |w|<=0.72) + 1 pk_add + 2 cvt + 2 add.
// Waves 1,2: producers — bulk-load a 64-step x chunk (one row/lane), compute
//   pre-scaled, pre-negated xW(t)+b into the xW ring; drain the h ring
//   (consumer output, 2 slots behind) to global.
// Lane layout: j = lane>>2 (hidden 0..15), g = lane&3 (gate i,f,g,o); row r = g*16+j.
// Only g==0 lanes' h is consumed (hpk readlanes 8p; drain reads 4*jj) — ia = own act.
template<int IN, bool LAST>
__global__ __launch_bounds__(192, 1) void bilstm_layer(
    const float* __restrict__ x,     // (B,T,IN)
    const float* __restrict__ Wih,   // (2,64,IN)
    const float* __restrict__ Whh,   // (2,64,16)
    const float* __restrict__ bias,  // (2,64)
    float* __restrict__ out)         // (B,T,32) or (B,256,32) if LAST
{
  constexpr int T = 2048;
  constexpr int C = 64;          // ring chunk (steps)
  constexpr int NCH = T / C;
  constexpr int NSLOT = NCH + 2; // xW produce -> consume -> h drain
  constexpr int NV4 = IN / 4;
  const int b    = blockIdx.x >> 1;
  const int dir  = blockIdx.x & 1;
  const int tid  = threadIdx.x;
  const int wave = tid >> 6;
  const int lane = tid & 63;
  const int g = lane & 3;
  const int r = g * 16 + (lane >> 2);
  // fold activation arg scale into weights/bias: gate lanes log2e, g-gate 2*log2e
  // (tanh = 2*sigmoid(2x)-1), negated so e = exp2(acc) directly.
  const float ksc = (g == 2) ? 2.0f * LOG2E : LOG2E;

  __shared__ float ring [2][(C + 2) * 64];  // xW staging (+2 rows: unguarded prefetch)
  __shared__ float ring2[2][C * 65];        // h staging (consumer -> drainers)

  if (wave >= 1) {
    // ---------------- producers ----------------
    const int pw = wave - 1;
    float wih[IN];
    const float* wr = Wih + (size_t)(dir * 64 + r) * IN;
#pragma unroll
    for (int k = 0; k < IN; ++k) wih[k] = -ksc * wr[k];
    const float bneg = -ksc * bias[dir * 64 + r];
    const float* xb = x + (size_t)b * T * IN;
    const int sl = lane >> 4;    // h-drain: step sub-row 0..3
    const int jj = lane & 15;    // h-drain: hidden index
    for (int c = 0; c < NSLOT; ++c) {
      // phase A: produce xW(chunk c)
      if (c < NCH) {
        const int tt0  = c * C;
        const int tmin = dir ? (T - C - tt0) : tt0;
        const float* src = xb + (size_t)(tmin + lane) * IN;
        float4 xr[NV4];
#pragma unroll
        for (int v = 0; v < NV4; ++v) xr[v] = *(const float4*)(src + 4 * v);
        float* buf = ring[c & 1];
        for (int s = pw; s < C; s += 2) {
          const int row = dir ? (C - 1 - s) : s;
          float a0 = bneg, a1 = 0.0f;
#pragma unroll
          for (int v = 0; v < NV4; ++v) {
            a0 = fmaf(rl(xr[v].x, row), wih[4 * v + 0], a0);
            a1 = fmaf(rl(xr[v].y, row), wih[4 * v + 1], a1);
            a0 = fmaf(rl(xr[v].z, row), wih[4 * v + 2], a0);
            a1 = fmaf(rl(xr[v].w, row), wih[4 * v + 3], a1);
          }
          buf[s * 64 + lane] = a0 + a1;   // = -ksc*(Wih·x_t + b)
        }
      }
      // phase B: drain h(chunk c-2) to global
      if (c >= 2 && c - 2 < NCH) {
        const int d = c - 2;
        const float* r2 = ring2[d & 1];
        for (int s0 = pw * 32; s0 < pw * 32 + 32; s0 += 4) {
          const int s  = s0 + sl;
          const float hv = r2[s * 65 + 4 * jj];
          const int tt = d * C + s;
          const int t  = dir ? (T - 1 - tt) : tt;
          if (!LAST) {
            out[((size_t)b * T + t) * 32 + dir * 16 + jj] = hv;
          } else if ((t & 7) == 7) {
            out[((size_t)b * 256 + (t >> 3)) * 32 + dir * 16 + jj] = hv;
          }
        }
      }
      __syncthreads();
    }
  } else {
    // ---------------- consumer (recurrence) ----------------
    h2t w2[8];
    {
      const float* wr = Whh + (size_t)(dir * 64 + r) * 16;
#pragma unroll
      for (int p = 0; p < 8; ++p) {
        h2t w;
        w.x = (_Float16)(-ksc * wr[2 * p]);
        w.y = (_Float16)(-ksc * wr[2 * p + 1]);
        w2[p] = w;
      }
    }
    // keep c scaled: ct = -2*log2e * c; extra scale folded into g-gate consts.
    const float amul = (g == 2) ? -4.0f * LOG2E : 1.0f;
    const float aadd = (g == 2) ?  2.0f * LOG2E : 0.0f;
    float ct = 0.0f, h = 0.0f;
    unsigned hpk = 0;   // f16 pair (h_{2p}, h_{2p+1}) valid on lanes 8p
    for (int c = 0; c < NSLOT; ++c) {
      if (c >= 1 && c <= NCH) {
        const float* bp = ring[(c - 1) & 1] + lane;
        float*       hb = ring2[(c - 1) & 1] + lane;
        float p0 = bp[0];
        float p1 = bp[64];
#pragma unroll 4
        for (int s = 0; s < C; ++s) {
          const float p2 = bp[(s + 2) * 64];          // distance-2 prefetch
          // 64x16 matvec: 8 h-pair broadcasts + 8 packed-f16 FMAs (2 chains)
          const unsigned q0 = rlu(hpk,  0);
          const unsigned q1 = rlu(hpk,  8);
          const unsigned q2 = rlu(hpk, 16);
          const unsigned q3 = rlu(hpk, 24);
          const unsigned q4 = rlu(hpk, 32);
          const unsigned q5 = rlu(hpk, 40);
          const unsigned q6 = rlu(hpk, 48);
          const unsigned q7 = rlu(hpk, 56);
          h2t aA = {(_Float16)0, (_Float16)0};
          h2t aB = {(_Float16)0, (_Float16)0};
          aA = __builtin_elementwise_fma(__builtin_bit_cast(h2t, q0), w2[0], aA);
          aB = __builtin_elementwise_fma(__builtin_bit_cast(h2t, q4), w2[4], aB);
          aA = __builtin_elementwise_fma(__builtin_bit_cast(h2t, q1), w2[1], aA);
          aB = __builtin_elementwise_fma(__builtin_bit_cast(h2t, q5), w2[5], aB);
          aA = __builtin_elementwise_fma(__builtin_bit_cast(h2t, q2), w2[2], aA);
          aB = __builtin_elementwise_fma(__builtin_bit_cast(h2t, q6), w2[6], aB);
          aA = __builtin_elementwise_fma(__builtin_bit_cast(h2t, q3), w2[3], aA);
          aB = __builtin_elementwise_fma(__builtin_bit_cast(h2t, q7), w2[7], aB);
          aA = aA + aB;                               // v_pk_add_f16
          const float m = (p0 + (float)aA.x) + (float)aA.y;   // = -ksc * preact
          const float e   = fast_exp2(m);
          const float sgm = fast_rcp(1.0f + e);       // sigmoid(ksc'*P)
          const float act = fmaf(sgm, amul, aadd);    // sigmoid / -2log2e*tanh
          const float fa = qb<0x55>(act);
          const float ga = qb<0xAA>(act);             // = -2log2e * g
          const float oa = qb<0xFF>(act);
          ct = fmaf(fa, ct, act * ga);                // act == ia on g=0 lanes
          const float e2 = fast_exp2(ct);
          const float tc = fmaf(fast_rcp(1.0f + e2), 2.0f, -1.0f);  // tanh(c)
          h = oa * tc;
          // pack (h_self, h_lane+4) f16 pair: row_shl:4 (lane i <- i+4), pkrtz
          const int hpart = __builtin_amdgcn_update_dpp(
              0, __float_as_int(h), 0x104, 0xF, 0xF, true);
          hpk = __builtin_bit_cast(unsigned,
              __builtin_amdgcn_cvt_pkrtz(h, __int_as_float(hpart)));
          hb[s * 65] = h;
          p0 = p1; p1 = p2;
        }
      }
      __syncthreads();
    }
  }
}

// Precompute layer-0 xW for the unidirectional stack: xw0[b][t][g] = ub0[g] + uWih0[g]·x
__global__ __launch_bounds__(256) void uni_xw0(
    const float* __restrict__ dsb,    // (B,256,32)
    const float* __restrict__ uWih0,  // (4,32)
    const float* __restrict__ ub,     // (4,4) — row 0 used
    float* __restrict__ xw0)          // (B,256,4)
{
  const int b = blockIdx.x;
  const int t = threadIdx.x;
  const float* xp = dsb + ((size_t)b * 256 + t) * 32;
  float xv[32];
#pragma unroll
  for (int k = 0; k < 32; k += 4) {
    const float4 v = *(const float4*)(xp + k);
    xv[k] = v.x; xv[k + 1] = v.y; xv[k + 2] = v.z; xv[k + 3] = v.w;
  }
  float4 o;
  float* po = &o.x;
#pragma unroll
  for (int gg = 0; gg < 4; ++gg) {
    float a0 = ub[gg], a1 = 0.f;
#pragma unroll
    for (int k = 0; k < 32; k += 2) {
      a0 = fmaf(uWih0[gg * 32 + k],     xv[k],     a0);
      a1 = fmaf(uWih0[gg * 32 + k + 1], xv[k + 1], a1);
    }
    po[gg] = a0 + a1;
  }
  *(float4*)(xw0 + ((size_t)b * 256 + t) * 4) = o;
}

// Fused 4-layer unidirectional stack (HU=1), step-synchronous across layers.
// lane = batch. Weights forced to SGPRs via readfirstlane; __launch_bounds__(64,1)
// grants the full VGPR budget (R4: VGPR_Count=16 -> everything spilled to scratch).
__global__ __launch_bounds__(64, 1) void uni_stack(
    const float* __restrict__ xw0,   // (B,256,4) pre-biased layer-0 xW
    const float* __restrict__ uWih,  // (3,4,1)
    const float* __restrict__ uWhh,  // (4,4,1)
    const float* __restrict__ ub,    // (4,4)
    float* __restrict__ out)         // (B,256)
{
  const int b = blockIdx.x * 64 + threadIdx.x;
  float whh[4][4], wih[3][4], bs[3][4];
#pragma unroll
  for (int l = 0; l < 4; ++l)
#pragma unroll
    for (int gg = 0; gg < 4; ++gg) whh[l][gg] = rfl(uWhh[l * 4 + gg]);
#pragma unroll
  for (int l = 0; l < 3; ++l)
#pragma unroll
    for (int gg = 0; gg < 4; ++gg) {
      wih[l][gg] = rfl(uWih[l * 4 + gg]);
      bs[l][gg]  = rfl(ub[(l + 1) * 4 + gg]);
    }
  float h[4] = {0, 0, 0, 0}, c[4] = {0, 0, 0, 0};
  const float4* xp = (const float4*)(xw0 + (size_t)b * 256 * 4);
  float* op = out + (size_t)b * 256;
  float4 cur = xp[0];
  for (int t = 0; t < 256; ++t) {
    const float4 nxt = xp[(t < 255) ? (t + 1) : 255];   // prefetch (guarded)
    {
      const float i0 = sigf(fmaf(whh[0][0], h[0], cur.x));
      const float f0 = sigf(fmaf(whh[0][1], h[0], cur.y));
      const float g0 = tanhfast(fmaf(whh[0][2], h[0], cur.z));
      const float o0 = sigf(fmaf(whh[0][3], h[0], cur.w));
      c[0] = fmaf(f0, c[0], i0 * g0);
      h[0] = o0 * tanhfast(c[0]);
    }
#pragma unroll
    for (int l = 1; l < 4; ++l) {
      const float xin = h[l - 1];
      const float pi  = fmaf(whh[l][0], h[l], fmaf(wih[l - 1][0], xin, bs[l - 1][0]));
      const float pf  = fmaf(whh[l][1], h[l], fmaf(wih[l - 1][1], xin, bs[l - 1][1]));
      const float pg  = fmaf(whh[l][2], h[l], fmaf(wih[l - 1][2], xin, bs[l - 1][2]));
      const float po_ = fmaf(whh[l][3], h[l], fmaf(wih[l - 1][3], xin, bs[l - 1][3]));
      const float il = sigf(pi), fl = sigf(pf), gl = tanhfast(pg), ol = sigf(po_);
      c[l] = fmaf(fl, c[l], il * gl);
      h[l] = ol * tanhfast(c[l]);
    }
    op[t] = h[3];
    cur = nxt;
  }
}

extern "C" void kernel_launch(void* const* d_in, const int* in_sizes, int n_in,
                              void* d_out, int out_size, void* d_ws, size_t ws_size,
                              hipStream_t stream)
{
  (void)in_sizes; (void)n_in; (void)out_size; (void)ws_size;
  const float* r_c_s = (const float*)d_in[0];
  const float* bWih0 = (const float*)d_in[1];
  const float* bWih  = (const float*)d_in[2];
  const float* bWhh  = (const float*)d_in[3];
  const float* bb    = (const float*)d_in[4];
  const float* uWih0 = (const float*)d_in[5];
  const float* uWih  = (const float*)d_in[6];
  const float* uWhh  = (const float*)d_in[7];
  const float* ub    = (const float*)d_in[8];
  float* outp = (float*)d_out;

  // workspace layout (floats): two (B,T,32) ping-pong, (B,256,32) downsample, (B,256,4) uni-xW
  float* x0  = (float*)d_ws;
  float* x1  = x0  + (size_t)128 * 2048 * 32;
  float* dsb = x1  + (size_t)128 * 2048 * 32;
  float* xw0 = dsb + (size_t)128 * 256 * 32;

  const dim3 grid(256), block(192);
  bilstm_layer<24, false><<<grid, block, 0, stream>>>(r_c_s, bWih0,               bWhh + 0,               bb + 0,          x0);
  bilstm_layer<32, false><<<grid, block, 0, stream>>>(x0,    bWih + 0 * 2*64*32,  bWhh + 1 * 2*64*16,     bb + 1 * 2*64,   x1);
  bilstm_layer<32, false><<<grid, block, 0, stream>>>(x1,    bWih + 1 * 2*64*32,  bWhh + 2 * 2*64*16,     bb + 2 * 2*64,   x0);
  bilstm_layer<32, true ><<<grid, block, 0, stream>>>(x0,    bWih + 2 * 2*64*32,  bWhh + 3 * 2*64*16,     bb + 3 * 2*64,   dsb);
  uni_xw0 <<<dim3(128), dim3(256), 0, stream>>>(dsb, uWih0, ub, xw0);
  uni_stack<<<dim3(2),   dim3(64),  0, stream>>>(xw0, uWih, uWhh, ub, outp);
}